// Round 1
// baseline (11333.707 us; speedup 1.0000x reference)
//
#include <hip/hip_runtime.h>

// GCLayer: out[dst] += (X @ W_k)[src] over 4 edge sets.
// N=100000 nodes, H=128, E=1.6M per edge set.

#define H 128

// ---------------------------------------------------------------------------
// GEMM: XW = X @ W   (X: [n,128] f32, W: [128,128] f32, XW: [n,128] f32)
// Block: 256 threads. W fully staged in LDS (64 KB). 32 X-rows per pass
// staged in LDS (padded stride 132 to avoid bank conflicts on the x reads).
// Thread t computes row (t>>3), cols [(t&7)*16 .. +16).
// ---------------------------------------------------------------------------
__global__ __launch_bounds__(256) void gemm_xw(const float* __restrict__ X,
                                               const float* __restrict__ W,
                                               float* __restrict__ XW, int n) {
  __shared__ float sW[128][128];   // 64 KB
  __shared__ float sX[32][132];    // 16.5 KB (padded)

  // cooperative load of W (16384 floats = 4096 float4, 16 per thread)
  {
    const float4* W4 = (const float4*)W;
    float4* sW4 = (float4*)(&sW[0][0]);
    for (int i = threadIdx.x; i < 128 * 32; i += 256) sW4[i] = W4[i];
  }

  const int rl = threadIdx.x >> 3;         // local row 0..31
  const int cg = (threadIdx.x & 7) << 4;   // col group 0,16,...,112

  for (int row0 = blockIdx.x * 32; row0 < n; row0 += gridDim.x * 32) {
    __syncthreads();  // sW visible (1st iter) / sX no longer read (later iters)
    // stage 32 rows of X (4096 floats = 1024 float4, 4 per thread)
    for (int i = threadIdx.x; i < 32 * 32; i += 256) {
      int r = i >> 5, c4 = (i & 31) << 2;
      int gr = row0 + r;
      float4 v = make_float4(0.f, 0.f, 0.f, 0.f);
      if (gr < n) v = ((const float4*)X)[(size_t)gr * 32 + (i & 31)];
      sX[r][c4 + 0] = v.x; sX[r][c4 + 1] = v.y;
      sX[r][c4 + 2] = v.z; sX[r][c4 + 3] = v.w;
    }
    __syncthreads();

    float acc[16];
#pragma unroll
    for (int i = 0; i < 16; ++i) acc[i] = 0.f;

#pragma unroll 4
    for (int k = 0; k < 128; ++k) {
      float xv = sX[rl][k];
#pragma unroll
      for (int i = 0; i < 16; ++i) acc[i] = fmaf(xv, sW[k][cg + i], acc[i]);
    }

    int grow = row0 + rl;
    if (grow < n) {
      float4* o = (float4*)&XW[(size_t)grow * H + cg];
      o[0] = make_float4(acc[0], acc[1], acc[2], acc[3]);
      o[1] = make_float4(acc[4], acc[5], acc[6], acc[7]);
      o[2] = make_float4(acc[8], acc[9], acc[10], acc[11]);
      o[3] = make_float4(acc[12], acc[13], acc[14], acc[15]);
    }
  }
}

// ---------------------------------------------------------------------------
// Scatter: for each edge e: out[dst[e]][:] += XW[src[e]][:]
// 32 threads per edge, float4 per thread, 4 fp32 atomics.
// ---------------------------------------------------------------------------
__global__ __launch_bounds__(256) void scatter_add(const float* __restrict__ XW,
                                                   const int* __restrict__ src,
                                                   const int* __restrict__ dst,
                                                   float* __restrict__ out,
                                                   int nE) {
  long long gid = (long long)blockIdx.x * 256 + threadIdx.x;
  int e = (int)(gid >> 5);
  if (e >= nE) return;
  int lane = (int)(gid & 31);
  int s = src[e];
  int d = dst[e];
  float4 v = ((const float4*)XW)[(size_t)s * 32 + lane];
  float* o = &out[(size_t)d * H + lane * 4];
  atomicAdd(o + 0, v.x);
  atomicAdd(o + 1, v.y);
  atomicAdd(o + 2, v.z);
  atomicAdd(o + 3, v.w);
}

// ---------------------------------------------------------------------------
extern "C" void kernel_launch(void* const* d_in, const int* in_sizes, int n_in,
                              void* d_out, int out_size, void* d_ws, size_t ws_size,
                              hipStream_t stream) {
  const float* X = (const float*)d_in[0];
  const int* edges[4] = {(const int*)d_in[1], (const int*)d_in[2],
                         (const int*)d_in[3], (const int*)d_in[4]};
  const float* Wk[4] = {(const float*)d_in[5], (const float*)d_in[6],
                        (const float*)d_in[7], (const float*)d_in[8]};
  float* out = (float*)d_out;
  float* XW = (float*)d_ws;  // needs n*H*4 bytes = 51.2 MB

  int n = in_sizes[0] / H;

  hipMemsetAsync(d_out, 0, (size_t)out_size * sizeof(float), stream);

  int gemm_grid = (n + 31) / 32;
  for (int k = 0; k < 4; ++k) {
    gemm_xw<<<gemm_grid, 256, 0, stream>>>(X, Wk[k], XW, n);
    int nE = in_sizes[1 + k] / 2;
    long long threads = (long long)nE * 32;
    int grid = (int)((threads + 255) / 256);
    scatter_add<<<grid, 256, 0, stream>>>(XW, edges[k], edges[k] + nE, out, nE);
  }
}

// Round 2
// 2308.353 us; speedup vs baseline: 4.9099x; 4.9099x over previous
//
#include <hip/hip_runtime.h>

// GCLayer: out[dst] += (X @ W_k)[src] over 4 edge sets.
// N=100000 nodes, H=128, E=1.6M per edge set.
// Round 2: replace fp32-atomic scatter with device-built CSR (by dst) +
// per-node wave gather (no fp atomics, write-once RMW per node).

#define H 128

// ---------------------------------------------------------------------------
// GEMM: XW = X @ W   (X: [n,128] f32, W: [128,128] f32, XW: [n,128] f32)
// ---------------------------------------------------------------------------
__global__ __launch_bounds__(256) void gemm_xw(const float* __restrict__ X,
                                               const float* __restrict__ W,
                                               float* __restrict__ XW, int n) {
  __shared__ float sW[128][128];   // 64 KB
  __shared__ float sX[32][132];    // padded

  {
    const float4* W4 = (const float4*)W;
    float4* sW4 = (float4*)(&sW[0][0]);
    for (int i = threadIdx.x; i < 128 * 32; i += 256) sW4[i] = W4[i];
  }

  const int rl = threadIdx.x >> 3;
  const int cg = (threadIdx.x & 7) << 4;

  for (int row0 = blockIdx.x * 32; row0 < n; row0 += gridDim.x * 32) {
    __syncthreads();
    for (int i = threadIdx.x; i < 32 * 32; i += 256) {
      int r = i >> 5, c4 = (i & 31) << 2;
      int gr = row0 + r;
      float4 v = make_float4(0.f, 0.f, 0.f, 0.f);
      if (gr < n) v = ((const float4*)X)[(size_t)gr * 32 + (i & 31)];
      sX[r][c4 + 0] = v.x; sX[r][c4 + 1] = v.y;
      sX[r][c4 + 2] = v.z; sX[r][c4 + 3] = v.w;
    }
    __syncthreads();

    float acc[16];
#pragma unroll
    for (int i = 0; i < 16; ++i) acc[i] = 0.f;

#pragma unroll 4
    for (int k = 0; k < 128; ++k) {
      float xv = sX[rl][k];
#pragma unroll
      for (int i = 0; i < 16; ++i) acc[i] = fmaf(xv, sW[k][cg + i], acc[i]);
    }

    int grow = row0 + rl;
    if (grow < n) {
      float4* o = (float4*)&XW[(size_t)grow * H + cg];
      o[0] = make_float4(acc[0], acc[1], acc[2], acc[3]);
      o[1] = make_float4(acc[4], acc[5], acc[6], acc[7]);
      o[2] = make_float4(acc[8], acc[9], acc[10], acc[11]);
      o[3] = make_float4(acc[12], acc[13], acc[14], acc[15]);
    }
  }
}

// ---------------------------------------------------------------------------
// CSR build: histogram of dst
// ---------------------------------------------------------------------------
__global__ __launch_bounds__(256) void hist_dst(const int* __restrict__ dst,
                                                int nE, int* __restrict__ cnt) {
  int i = blockIdx.x * 256 + threadIdx.x;
  if (i < nE) atomicAdd(&cnt[dst[i]], 1);
}

// ---------------------------------------------------------------------------
// Single-block exclusive scan of cnt[0..n) -> row_ptr[0..n]; also copies the
// exclusive prefix into cursor (in-place over cnt) for the scatter pass.
// 1024 threads = 16 waves; shfl-scan within wave, LDS across waves.
// ---------------------------------------------------------------------------
__global__ __launch_bounds__(1024) void scan_cnt(int* __restrict__ cnt_cursor,
                                                 int* __restrict__ row_ptr, int n) {
  __shared__ int wsum[16];
  __shared__ int s_total;
  const int t = threadIdx.x, lane = t & 63, wid = t >> 6;
  int carry = 0;
  for (int base = 0; base < n; base += 1024) {
    int i = base + t;
    int v = (i < n) ? cnt_cursor[i] : 0;
    int incl = v;
#pragma unroll
    for (int d = 1; d < 64; d <<= 1) {
      int x = __shfl_up(incl, d, 64);
      if (lane >= d) incl += x;
    }
    if (lane == 63) wsum[wid] = incl;
    __syncthreads();
    if (wid == 0 && lane < 16) {
      int w = wsum[lane];
      int wincl = w;
#pragma unroll
      for (int d = 1; d < 16; d <<= 1) {
        int x = __shfl_up(wincl, d, 16);
        if (lane >= d) wincl += x;
      }
      wsum[lane] = wincl - w;          // exclusive offset of this wave
      if (lane == 15) s_total = wincl; // chunk total
    }
    __syncthreads();
    int excl = carry + wsum[wid] + (incl - v);
    if (i < n) { row_ptr[i] = excl; cnt_cursor[i] = excl; }
    int chunk_total = s_total;
    __syncthreads();                   // protect wsum/s_total before next iter
    carry += chunk_total;
  }
  if (t == 0) row_ptr[n] = carry;
}

// ---------------------------------------------------------------------------
// CSR build: scatter edge src ids into col_idx at cursor positions
// ---------------------------------------------------------------------------
__global__ __launch_bounds__(256) void scatter_idx(const int* __restrict__ src,
                                                   const int* __restrict__ dst,
                                                   int nE,
                                                   int* __restrict__ cursor,
                                                   int* __restrict__ col_idx) {
  int i = blockIdx.x * 256 + threadIdx.x;
  if (i < nE) {
    int pos = atomicAdd(&cursor[dst[i]], 1);
    col_idx[pos] = src[i];
  }
}

// ---------------------------------------------------------------------------
// Gather: one wave per node. out[n][:] += sum over in-edges XW[src][:]
// Each lane owns 2 floats (float2): 512 B coalesced per row read.
// ---------------------------------------------------------------------------
__global__ __launch_bounds__(256) void gather_acc(const float* __restrict__ XW,
                                                  const int* __restrict__ row_ptr,
                                                  const int* __restrict__ col_idx,
                                                  float* __restrict__ out, int n) {
  int wave = (int)((blockIdx.x * 256 + threadIdx.x) >> 6);
  int lane = threadIdx.x & 63;
  if (wave >= n) return;
  int beg = row_ptr[wave], end = row_ptr[wave + 1];
  float2 a0 = make_float2(0.f, 0.f);
  float2 a1 = make_float2(0.f, 0.f);
  int j = beg;
  for (; j + 1 < end; j += 2) {
    int s0 = col_idx[j], s1 = col_idx[j + 1];
    float2 v0 = ((const float2*)XW)[(size_t)s0 * 64 + lane];
    float2 v1 = ((const float2*)XW)[(size_t)s1 * 64 + lane];
    a0.x += v0.x; a0.y += v0.y;
    a1.x += v1.x; a1.y += v1.y;
  }
  if (j < end) {
    int s0 = col_idx[j];
    float2 v0 = ((const float2*)XW)[(size_t)s0 * 64 + lane];
    a0.x += v0.x; a0.y += v0.y;
  }
  float2* o = (float2*)&out[(size_t)wave * H + lane * 2];
  float2 cur = *o;
  cur.x += a0.x + a1.x;
  cur.y += a0.y + a1.y;
  *o = cur;
}

// ---------------------------------------------------------------------------
extern "C" void kernel_launch(void* const* d_in, const int* in_sizes, int n_in,
                              void* d_out, int out_size, void* d_ws, size_t ws_size,
                              hipStream_t stream) {
  const float* X = (const float*)d_in[0];
  const int* edges[4] = {(const int*)d_in[1], (const int*)d_in[2],
                         (const int*)d_in[3], (const int*)d_in[4]};
  const float* Wk[4] = {(const float*)d_in[5], (const float*)d_in[6],
                        (const float*)d_in[7], (const float*)d_in[8]};
  float* out = (float*)d_out;

  int n = in_sizes[0] / H;

  // workspace layout
  char* ws = (char*)d_ws;
  float* XW = (float*)ws;                                   // n*H*4 = 51.2 MB
  size_t off = (size_t)n * H * sizeof(float);
  int* row_ptr = (int*)(ws + off);                          // (n+1) ints
  off += ((size_t)(n + 1) * sizeof(int) + 511) & ~511ull;
  int* cursor = (int*)(ws + off);                           // n ints (also hist)
  off += ((size_t)n * sizeof(int) + 511) & ~511ull;
  int* col_idx = (int*)(ws + off);                          // nE ints

  hipMemsetAsync(d_out, 0, (size_t)out_size * sizeof(float), stream);

  int gemm_grid = (n + 31) / 32;
  int gather_grid = (n * 64 + 255) / 256;  // one wave per node

  for (int k = 0; k < 4; ++k) {
    int nE = in_sizes[1 + k] / 2;
    const int* src = edges[k];
    const int* dst = edges[k] + nE;

    gemm_xw<<<gemm_grid, 256, 0, stream>>>(X, Wk[k], XW, n);

    hipMemsetAsync(cursor, 0, (size_t)n * sizeof(int), stream);
    hist_dst<<<(nE + 255) / 256, 256, 0, stream>>>(dst, nE, cursor);
    scan_cnt<<<1, 1024, 0, stream>>>(cursor, row_ptr, n);
    scatter_idx<<<(nE + 255) / 256, 256, 0, stream>>>(src, dst, nE, cursor, col_idx);

    gather_acc<<<gather_grid, 256, 0, stream>>>(XW, row_ptr, col_idx, out, n);
  }
}

// Round 3
// 1158.094 us; speedup vs baseline: 9.7865x; 1.9932x over previous
//
#include <hip/hip_runtime.h>

// GCLayer: out[dst] += (X @ W_k)[src] over 4 edge sets.
// N=100000, H=128, E=1.6M per set.
// Round 3: bf16 MFMA GEMM, bf16 XW table, one fused CSR over all 4 edge sets.

#define H 128

typedef __bf16 bf16x8 __attribute__((ext_vector_type(8)));
typedef float f32x4 __attribute__((ext_vector_type(4)));

static __device__ __forceinline__ ushort f2bf(float f) {
  union { float f; uint u; } v; v.f = f;
  uint r = (v.u + 0x7FFFu + ((v.u >> 16) & 1u)) >> 16;
  return (ushort)r;
}
static __device__ __forceinline__ float bflo(uint u) {
  union { uint u; float f; } v; v.u = u << 16; return v.f;
}
static __device__ __forceinline__ float bfhi(uint u) {
  union { uint u; float f; } v; v.u = u & 0xFFFF0000u; return v.f;
}

// ---------------------------------------------------------------------------
// Wt[k][c][kk] = bf16(W_k[kk][c])  (transpose + convert, 65536 elements)
// ---------------------------------------------------------------------------
__global__ __launch_bounds__(256) void prep_w(const float* __restrict__ W0,
                                              const float* __restrict__ W1,
                                              const float* __restrict__ W2,
                                              const float* __restrict__ W3,
                                              ushort* __restrict__ Wt) {
  int idx = blockIdx.x * 256 + threadIdx.x;   // 0..65535
  int kk = idx & 127;
  int c = (idx >> 7) & 127;
  int k = idx >> 14;
  const float* W = (k == 0) ? W0 : (k == 1) ? W1 : (k == 2) ? W2 : W3;
  Wt[idx] = f2bf(W[kk * 128 + c]);
}

// ---------------------------------------------------------------------------
// MFMA GEMM: XW[slice] = bf16( X @ W_{kBase+blockIdx.y} )
// 256 threads = 4 waves; 64 rows/block; full K=128, N=128 per wave-row-tile.
// mfma_f32_16x16x32_bf16: A row=lane&15, k=(lane>>4)*8+j; B col=lane&15, same k;
// D row=(lane>>4)*4+reg, col=lane&15  [verified layout, learn_hip m89/m91].
// ---------------------------------------------------------------------------
__global__ __launch_bounds__(256) void gemm_mfma(const float* __restrict__ X,
                                                 const ushort* __restrict__ Wt,
                                                 ushort* __restrict__ XW,
                                                 int n, int kBase,
                                                 long long sliceStride) {
  // padded bf16 row stride 144 (=288 B, 16B-aligned for b128 reads)
  __shared__ __align__(16) ushort sX[64][144];
  __shared__ __align__(16) ushort sW[128][144];

  int k = kBase + blockIdx.y;
  const ushort* Wk = Wt + (size_t)k * 16384;
  int row0 = blockIdx.x * 64;

  // stage W^T slice: 128x128 bf16 via uint4 (8 bf16 each), 2048 loads
  for (int i = threadIdx.x; i < 2048; i += 256) {
    int r = i >> 4, q = i & 15;
    uint4 v = ((const uint4*)Wk)[i];
    *(uint4*)&sW[r][q * 8] = v;
  }
  // stage X tile: 64x128 f32 -> bf16, 2048 float4 loads
  for (int i = threadIdx.x; i < 2048; i += 256) {
    int r = i >> 5, q = i & 31;
    int gr = row0 + r;
    float4 v = make_float4(0.f, 0.f, 0.f, 0.f);
    if (gr < n) v = ((const float4*)X)[(size_t)gr * 32 + q];
    uint2 p;
    p.x = (uint)f2bf(v.x) | ((uint)f2bf(v.y) << 16);
    p.y = (uint)f2bf(v.z) | ((uint)f2bf(v.w) << 16);
    *(uint2*)&sX[r][q * 4] = p;
  }
  __syncthreads();

  int w = threadIdx.x >> 6;
  int l = threadIdx.x & 63;
  int lr = l & 15;
  int lg = l >> 4;

  f32x4 acc[8];
#pragma unroll
  for (int i = 0; i < 8; ++i) acc[i] = (f32x4)0.f;

#pragma unroll
  for (int kk = 0; kk < 4; ++kk) {
    bf16x8 a = *(const bf16x8*)&sX[w * 16 + lr][kk * 32 + lg * 8];
#pragma unroll
    for (int nf = 0; nf < 8; ++nf) {
      bf16x8 b = *(const bf16x8*)&sW[nf * 16 + lr][kk * 32 + lg * 8];
      acc[nf] = __builtin_amdgcn_mfma_f32_16x16x32_bf16(a, b, acc[nf], 0, 0, 0);
    }
  }

  ushort* outb = XW + (size_t)blockIdx.y * sliceStride;
#pragma unroll
  for (int nf = 0; nf < 8; ++nf) {
#pragma unroll
    for (int r = 0; r < 4; ++r) {
      int row = row0 + w * 16 + lg * 4 + r;
      if (row < n) outb[(size_t)row * H + nf * 16 + lr] = f2bf(acc[nf][r]);
    }
  }
}

// ---------------------------------------------------------------------------
// CSR build
// ---------------------------------------------------------------------------
__global__ __launch_bounds__(256) void hist_dst(const int* __restrict__ dst,
                                                int nE, int* __restrict__ cnt) {
  int i = blockIdx.x * 256 + threadIdx.x;
  if (i < nE) atomicAdd(&cnt[dst[i]], 1);
}

__global__ __launch_bounds__(1024) void scan_cnt(int* __restrict__ cnt_cursor,
                                                 int* __restrict__ row_ptr, int n) {
  __shared__ int wsum[16];
  __shared__ int s_total;
  const int t = threadIdx.x, lane = t & 63, wid = t >> 6;
  int carry = 0;
  for (int base = 0; base < n; base += 1024) {
    int i = base + t;
    int v = (i < n) ? cnt_cursor[i] : 0;
    int incl = v;
#pragma unroll
    for (int d = 1; d < 64; d <<= 1) {
      int x = __shfl_up(incl, d, 64);
      if (lane >= d) incl += x;
    }
    if (lane == 63) wsum[wid] = incl;
    __syncthreads();
    if (wid == 0 && lane < 16) {
      int w = wsum[lane];
      int wincl = w;
#pragma unroll
      for (int d = 1; d < 16; d <<= 1) {
        int x = __shfl_up(wincl, d, 16);
        if (lane >= d) wincl += x;
      }
      wsum[lane] = wincl - w;
      if (lane == 15) s_total = wincl;
    }
    __syncthreads();
    int excl = carry + wsum[wid] + (incl - v);
    if (i < n) { row_ptr[i] = excl; cnt_cursor[i] = excl; }
    int chunk_total = s_total;
    __syncthreads();
    carry += chunk_total;
  }
  if (t == 0) row_ptr[n] = carry;
}

__global__ __launch_bounds__(256) void scatter_idx(const int* __restrict__ src,
                                                   const int* __restrict__ dst,
                                                   int nE, int kbase,
                                                   int* __restrict__ cursor,
                                                   int* __restrict__ col_idx) {
  int i = blockIdx.x * 256 + threadIdx.x;
  if (i < nE) {
    int pos = atomicAdd(&cursor[dst[i]], 1);
    col_idx[pos] = kbase + src[i];
  }
}

// ---------------------------------------------------------------------------
// Gather: one wave per node; lane owns 2 cols (one uint = 2 bf16 per row read).
// ---------------------------------------------------------------------------
__global__ __launch_bounds__(256) void gather_bf16(const ushort* __restrict__ XW,
                                                   const int* __restrict__ row_ptr,
                                                   const int* __restrict__ col_idx,
                                                   float* __restrict__ out,
                                                   int n, int accum) {
  int wave = (int)((blockIdx.x * 256 + threadIdx.x) >> 6);
  int lane = threadIdx.x & 63;
  if (wave >= n) return;
  int beg = row_ptr[wave], end = row_ptr[wave + 1];
  float a0 = 0.f, a1 = 0.f, b0 = 0.f, b1 = 0.f;
  int j = beg;
  for (; j + 3 < end; j += 4) {
    int c0 = col_idx[j], c1 = col_idx[j + 1];
    int c2 = col_idx[j + 2], c3 = col_idx[j + 3];
    uint u0 = *(const uint*)&XW[(size_t)c0 * H + lane * 2];
    uint u1 = *(const uint*)&XW[(size_t)c1 * H + lane * 2];
    uint u2 = *(const uint*)&XW[(size_t)c2 * H + lane * 2];
    uint u3 = *(const uint*)&XW[(size_t)c3 * H + lane * 2];
    a0 += bflo(u0); a1 += bfhi(u0);
    b0 += bflo(u1); b1 += bfhi(u1);
    a0 += bflo(u2); a1 += bfhi(u2);
    b0 += bflo(u3); b1 += bfhi(u3);
  }
  for (; j < end; ++j) {
    uint u = *(const uint*)&XW[(size_t)col_idx[j] * H + lane * 2];
    a0 += bflo(u); a1 += bfhi(u);
  }
  float r0 = a0 + b0, r1 = a1 + b1;
  float* o = &out[(size_t)wave * H + lane * 2];
  if (accum) { r0 += o[0]; r1 += o[1]; }
  o[0] = r0; o[1] = r1;
}

// ---------------------------------------------------------------------------
extern "C" void kernel_launch(void* const* d_in, const int* in_sizes, int n_in,
                              void* d_out, int out_size, void* d_ws, size_t ws_size,
                              hipStream_t stream) {
  const float* X = (const float*)d_in[0];
  const int* edges[4] = {(const int*)d_in[1], (const int*)d_in[2],
                         (const int*)d_in[3], (const int*)d_in[4]};
  const float* Wk[4] = {(const float*)d_in[5], (const float*)d_in[6],
                        (const float*)d_in[7], (const float*)d_in[8]};
  float* out = (float*)d_out;

  int n = in_sizes[0] / H;
  int nE[4];
  long long totE = 0;
  int maxE = 0;
  for (int k = 0; k < 4; ++k) {
    nE[k] = in_sizes[1 + k] / 2;
    totE += nE[k];
    if (nE[k] > maxE) maxE = nE[k];
  }

  // workspace layout
  char* ws = (char*)d_ws;
  size_t off = 0;
  auto take = [&](size_t bytes) -> char* {
    char* p = ws + off;
    off = (off + bytes + 255) & ~(size_t)255;
    return p;
  };
  ushort* Wt = (ushort*)take(4 * 128 * 128 * sizeof(ushort));
  int* row_ptr = (int*)take((size_t)(n + 1) * sizeof(int));
  int* cursor = (int*)take((size_t)n * sizeof(int));
  size_t fixed = off;

  size_t fused_need = fixed + (size_t)totE * sizeof(int) + (size_t)4 * n * H * sizeof(ushort);
  bool fused = (ws_size >= fused_need);

  int gemm_gx = (n + 63) / 64;
  int gather_grid = (int)(((long long)n * 64 + 255) / 256);

  prep_w<<<256, 256, 0, stream>>>(Wk[0], Wk[1], Wk[2], Wk[3], Wt);

  if (fused) {
    int* col_idx = (int*)take((size_t)totE * sizeof(int));
    ushort* XW = (ushort*)take((size_t)4 * n * H * sizeof(ushort));

    gemm_mfma<<<dim3(gemm_gx, 4), 256, 0, stream>>>(X, Wt, XW, n, 0,
                                                    (long long)n * H);

    hipMemsetAsync(cursor, 0, (size_t)n * sizeof(int), stream);
    for (int k = 0; k < 4; ++k)
      hist_dst<<<(nE[k] + 255) / 256, 256, 0, stream>>>(edges[k] + nE[k], nE[k], cursor);
    scan_cnt<<<1, 1024, 0, stream>>>(cursor, row_ptr, n);
    for (int k = 0; k < 4; ++k)
      scatter_idx<<<(nE[k] + 255) / 256, 256, 0, stream>>>(edges[k], edges[k] + nE[k],
                                                           nE[k], k * n, cursor, col_idx);

    gather_bf16<<<gather_grid, 256, 0, stream>>>(XW, row_ptr, col_idx, out, n, 0);
  } else {
    // per-set fallback (ws >= ~34 MB)
    int* col_idx = (int*)take((size_t)maxE * sizeof(int));
    ushort* XW = (ushort*)take((size_t)n * H * sizeof(ushort));

    hipMemsetAsync(out, 0, (size_t)n * H * sizeof(float), stream);
    for (int k = 0; k < 4; ++k) {
      gemm_mfma<<<dim3(gemm_gx, 1), 256, 0, stream>>>(X, Wt, XW, n, k, 0);
      hipMemsetAsync(cursor, 0, (size_t)n * sizeof(int), stream);
      hist_dst<<<(nE[k] + 255) / 256, 256, 0, stream>>>(edges[k] + nE[k], nE[k], cursor);
      scan_cnt<<<1, 1024, 0, stream>>>(cursor, row_ptr, n);
      scatter_idx<<<(nE[k] + 255) / 256, 256, 0, stream>>>(edges[k], edges[k] + nE[k],
                                                           nE[k], 0, cursor, col_idx);
      gather_bf16<<<gather_grid, 256, 0, stream>>>(XW, row_ptr, col_idx, out, n, 1);
    }
  }
}

// Round 4
// 1076.827 us; speedup vs baseline: 10.5251x; 1.0755x over previous
//
#include <hip/hip_runtime.h>

// GCLayer: out[dst] += (X @ W_k)[src] over 4 edge sets.
// Round 4: aggregate-first (S_k[dst] = sum X[src]; out = concat_k(S_k) @ stack_k(W_k)),
// bf16 X table (25.6 MB, L2/L3-friendly), one combined CSR, 3-pass scan,
// node-chunked gather+GEMM to fit workspace.

#define H 128

typedef __bf16 bf16x8 __attribute__((ext_vector_type(8)));
typedef float f32x4 __attribute__((ext_vector_type(4)));

static __device__ __forceinline__ ushort f2bf(float f) {
  union { float f; uint u; } v; v.f = f;
  uint r = (v.u + 0x7FFFu + ((v.u >> 16) & 1u)) >> 16;
  return (ushort)r;
}
static __device__ __forceinline__ float bflo(uint u) {
  union { uint u; float f; } v; v.u = u << 16; return v.f;
}
static __device__ __forceinline__ float bfhi(uint u) {
  union { uint u; float f; } v; v.u = u & 0xFFFF0000u; return v.f;
}

// ---------------------------------------------------------------------------
// Wt[k][c][kk] = bf16(W_k[kk][c])  (transpose + convert)
// ---------------------------------------------------------------------------
__global__ __launch_bounds__(256) void prep_w(const float* __restrict__ W0,
                                              const float* __restrict__ W1,
                                              const float* __restrict__ W2,
                                              const float* __restrict__ W3,
                                              ushort* __restrict__ Wt) {
  int idx = blockIdx.x * 256 + threadIdx.x;   // 0..65535
  int kk = idx & 127;
  int c = (idx >> 7) & 127;
  int k = idx >> 14;
  const float* W = (k == 0) ? W0 : (k == 1) ? W1 : (k == 2) ? W2 : W3;
  Wt[idx] = f2bf(W[kk * 128 + c]);
}

// ---------------------------------------------------------------------------
// Xb = bf16(X), packed 2 per uint
// ---------------------------------------------------------------------------
__global__ __launch_bounds__(256) void conv_x(const float4* __restrict__ X4,
                                              uint2* __restrict__ Xb2, int m) {
  int i = blockIdx.x * 256 + threadIdx.x;
  if (i < m) {
    float4 v = X4[i];
    uint2 p;
    p.x = (uint)f2bf(v.x) | ((uint)f2bf(v.y) << 16);
    p.y = (uint)f2bf(v.z) | ((uint)f2bf(v.w) << 16);
    Xb2[i] = p;
  }
}

// ---------------------------------------------------------------------------
// CSR build (combined over all 4 edge sets; segments = dst node)
// ---------------------------------------------------------------------------
__global__ __launch_bounds__(256) void hist_dst(const int* __restrict__ dst,
                                                int nE, int* __restrict__ cnt) {
  int i = blockIdx.x * 256 + threadIdx.x;
  if (i < nE) atomicAdd(&cnt[dst[i]], 1);
}

// 3-pass decoupled scan ------------------------------------------------------
__global__ __launch_bounds__(1024) void scan_blocks(const int* __restrict__ cnt,
                                                    int* __restrict__ row_ptr,
                                                    int* __restrict__ bsum, int n) {
  __shared__ int wsum[16];
  const int t = threadIdx.x, lane = t & 63, wid = t >> 6;
  int i = blockIdx.x * 1024 + t;
  int v = (i < n) ? cnt[i] : 0;
  int incl = v;
#pragma unroll
  for (int d = 1; d < 64; d <<= 1) {
    int x = __shfl_up(incl, d, 64);
    if (lane >= d) incl += x;
  }
  if (lane == 63) wsum[wid] = incl;
  __syncthreads();
  if (wid == 0 && lane < 16) {
    int w = wsum[lane];
    int wincl = w;
#pragma unroll
    for (int d = 1; d < 16; d <<= 1) {
      int x = __shfl_up(wincl, d, 16);
      if (lane >= d) wincl += x;
    }
    wsum[lane] = wincl - w;   // exclusive wave offset
  }
  __syncthreads();
  int excl = wsum[wid] + (incl - v);
  if (i < n) row_ptr[i] = excl;
  if (t == 1023) bsum[blockIdx.x] = excl + v;   // block total
}

__global__ __launch_bounds__(1024) void scan_bsums(int* __restrict__ bsum,
                                                   int* __restrict__ row_ptr,
                                                   int G, int n) {
  __shared__ int wsum[16];
  const int t = threadIdx.x, lane = t & 63, wid = t >> 6;
  int v = (t < G) ? bsum[t] : 0;
  int incl = v;
#pragma unroll
  for (int d = 1; d < 64; d <<= 1) {
    int x = __shfl_up(incl, d, 64);
    if (lane >= d) incl += x;
  }
  if (lane == 63) wsum[wid] = incl;
  __syncthreads();
  if (wid == 0 && lane < 16) {
    int w = wsum[lane];
    int wincl = w;
#pragma unroll
    for (int d = 1; d < 16; d <<= 1) {
      int x = __shfl_up(wincl, d, 16);
      if (lane >= d) wincl += x;
    }
    wsum[lane] = wincl - w;
  }
  __syncthreads();
  int excl = wsum[wid] + (incl - v);
  if (t < G) bsum[t] = excl;
  if (t == G - 1) row_ptr[n] = excl + v;   // grand total
}

__global__ __launch_bounds__(256) void scan_add(int* __restrict__ row_ptr,
                                                int* __restrict__ cursor,
                                                const int* __restrict__ bsum, int n) {
  int i = blockIdx.x * 256 + threadIdx.x;
  if (i < n) {
    int r = row_ptr[i] + bsum[i >> 10];
    row_ptr[i] = r;
    cursor[i] = r;
  }
}

// scatter src ids tagged with edge-set k into col_idx -----------------------
__global__ __launch_bounds__(256) void scatter_idx(const int* __restrict__ src,
                                                   const int* __restrict__ dst,
                                                   int nE, int ktag,
                                                   int* __restrict__ cursor,
                                                   int* __restrict__ col_idx) {
  int i = blockIdx.x * 256 + threadIdx.x;
  if (i < nE) {
    int pos = atomicAdd(&cursor[dst[i]], 1);
    col_idx[pos] = (ktag << 28) | src[i];
  }
}

// ---------------------------------------------------------------------------
// Gather-aggregate: one wave per node; 4 per-k accumulators (2 cols/lane).
// Writes S[node-n0][512] bf16 (concat of the 4 k-slices along K).
// ---------------------------------------------------------------------------
#define ACC_ADD(kk, u) do { float lo_ = bflo(u), hi_ = bfhi(u);          \
    if ((kk) == 0) { a0x += lo_; a0y += hi_; }                            \
    else if ((kk) == 1) { a1x += lo_; a1y += hi_; }                       \
    else if ((kk) == 2) { a2x += lo_; a2y += hi_; }                       \
    else { a3x += lo_; a3y += hi_; } } while (0)

__global__ __launch_bounds__(256) void gather_agg(const uint* __restrict__ Xb,
                                                  const int* __restrict__ row_ptr,
                                                  const int* __restrict__ col_idx,
                                                  uint* __restrict__ S,
                                                  int n0, int n1) {
  int node = n0 + (int)((blockIdx.x * 256 + threadIdx.x) >> 6);
  if (node >= n1) return;
  int lane = threadIdx.x & 63;
  int beg = row_ptr[node], end = row_ptr[node + 1];
  float a0x = 0.f, a0y = 0.f, a1x = 0.f, a1y = 0.f;
  float a2x = 0.f, a2y = 0.f, a3x = 0.f, a3y = 0.f;
  int j = beg;
  for (; j + 3 < end; j += 4) {
    int c0 = col_idx[j], c1 = col_idx[j + 1];
    int c2 = col_idx[j + 2], c3 = col_idx[j + 3];
    uint u0 = Xb[(size_t)(c0 & 0x0FFFFFFF) * 64 + lane];
    uint u1 = Xb[(size_t)(c1 & 0x0FFFFFFF) * 64 + lane];
    uint u2 = Xb[(size_t)(c2 & 0x0FFFFFFF) * 64 + lane];
    uint u3 = Xb[(size_t)(c3 & 0x0FFFFFFF) * 64 + lane];
    int k0 = (uint)c0 >> 28, k1 = (uint)c1 >> 28;
    int k2 = (uint)c2 >> 28, k3 = (uint)c3 >> 28;
    ACC_ADD(k0, u0); ACC_ADD(k1, u1); ACC_ADD(k2, u2); ACC_ADD(k3, u3);
  }
  for (; j < end; ++j) {
    int c = col_idx[j];
    uint u = Xb[(size_t)(c & 0x0FFFFFFF) * 64 + lane];
    int k = (uint)c >> 28;
    ACC_ADD(k, u);
  }
  size_t rb = (size_t)(node - n0) * 256;   // 512 bf16 = 256 uints per row
  S[rb + 0 * 64 + lane] = (uint)f2bf(a0x) | ((uint)f2bf(a0y) << 16);
  S[rb + 1 * 64 + lane] = (uint)f2bf(a1x) | ((uint)f2bf(a1y) << 16);
  S[rb + 2 * 64 + lane] = (uint)f2bf(a2x) | ((uint)f2bf(a2y) << 16);
  S[rb + 3 * 64 + lane] = (uint)f2bf(a3x) | ((uint)f2bf(a3y) << 16);
}

// ---------------------------------------------------------------------------
// Final GEMM: out[n0:n1] = S @ concat_k(W_k)   (K=512, bf16 MFMA, fp32 out)
// 4 waves, 64 rows/block, K-chunk loop of 4 x 128.
// ---------------------------------------------------------------------------
__global__ __launch_bounds__(256) void gemm_final(const ushort* __restrict__ S,
                                                  const ushort* __restrict__ Wt,
                                                  float* __restrict__ out,
                                                  int n0, int n1) {
  __shared__ __align__(16) ushort sX[64][136];   // stride 272 B (2-way banks)
  __shared__ __align__(16) ushort sW[128][136];

  int row0 = n0 + blockIdx.x * 64;
  int w = threadIdx.x >> 6;
  int l = threadIdx.x & 63;
  int lr = l & 15;
  int lg = l >> 4;

  f32x4 acc[8];
#pragma unroll
  for (int i = 0; i < 8; ++i) acc[i] = (f32x4)0.f;

  for (int kc = 0; kc < 4; ++kc) {
    __syncthreads();
    // stage S tile: 64 rows x 128 bf16 (1024 uint4)
    for (int i = threadIdx.x; i < 1024; i += 256) {
      int r = i >> 4, q = i & 15;
      int gr = row0 + r;
      uint4 v = make_uint4(0u, 0u, 0u, 0u);
      if (gr < n1) v = ((const uint4*)S)[(size_t)(gr - n0) * 64 + kc * 16 + q];
      *(uint4*)&sX[r][q * 8] = v;
    }
    // stage W chunk: 128 x 128 bf16 (2048 uint4)
    for (int i = threadIdx.x; i < 2048; i += 256) {
      int r = i >> 4, q = i & 15;
      uint4 v = ((const uint4*)Wt)[kc * 2048 + i];
      *(uint4*)&sW[r][q * 8] = v;
    }
    __syncthreads();

#pragma unroll
    for (int kk = 0; kk < 4; ++kk) {
      bf16x8 a = *(const bf16x8*)&sX[w * 16 + lr][kk * 32 + lg * 8];
#pragma unroll
      for (int nf = 0; nf < 8; ++nf) {
        bf16x8 b = *(const bf16x8*)&sW[nf * 16 + lr][kk * 32 + lg * 8];
        acc[nf] = __builtin_amdgcn_mfma_f32_16x16x32_bf16(a, b, acc[nf], 0, 0, 0);
      }
    }
  }

#pragma unroll
  for (int nf = 0; nf < 8; ++nf) {
#pragma unroll
    for (int r = 0; r < 4; ++r) {
      int row = row0 + w * 16 + lg * 4 + r;
      if (row < n1) out[(size_t)row * H + nf * 16 + lr] = acc[nf][r];
    }
  }
}

// ---------------------------------------------------------------------------
extern "C" void kernel_launch(void* const* d_in, const int* in_sizes, int n_in,
                              void* d_out, int out_size, void* d_ws, size_t ws_size,
                              hipStream_t stream) {
  const float* X = (const float*)d_in[0];
  const int* edges[4] = {(const int*)d_in[1], (const int*)d_in[2],
                         (const int*)d_in[3], (const int*)d_in[4]};
  const float* Wk[4] = {(const float*)d_in[5], (const float*)d_in[6],
                        (const float*)d_in[7], (const float*)d_in[8]};
  float* out = (float*)d_out;

  int n = in_sizes[0] / H;
  int nE[4];
  long long totE = 0;
  for (int k = 0; k < 4; ++k) {
    nE[k] = in_sizes[1 + k] / 2;
    totE += nE[k];
  }
  int nb = (n + 1023) / 1024;

  // workspace layout
  char* ws = (char*)d_ws;
  size_t off = 0;
  auto take = [&](size_t bytes) -> char* {
    char* p = ws + off;
    off = (off + bytes + 255) & ~(size_t)255;
    return p;
  };
  ushort* Wt = (ushort*)take(4 * 128 * 128 * sizeof(ushort));
  int* row_ptr = (int*)take((size_t)(n + 1) * sizeof(int));
  int* cursor = (int*)take((size_t)n * sizeof(int));
  int* bsum = (int*)take((size_t)nb * sizeof(int));
  uint* Xb = (uint*)take((size_t)n * H * sizeof(ushort));
  int* col_idx = (int*)take((size_t)totE * sizeof(int));
  ushort* S = (ushort*)(ws + off);
  size_t s_avail = (ws_size > off) ? (ws_size - off) : 0;

  // node chunking so S (1024 B/node) fits in remaining workspace
  int chunk_rows = (int)(s_avail / 1024);
  if (chunk_rows > n) chunk_rows = n;
  if (chunk_rows < 1024) chunk_rows = 1024;   // should not happen
  chunk_rows &= ~63;                          // multiple of 64

  prep_w<<<256, 256, 0, stream>>>(Wk[0], Wk[1], Wk[2], Wk[3], Wt);
  conv_x<<<(n * 32 + 255) / 256, 256, 0, stream>>>((const float4*)X, (uint2*)Xb, n * 32);

  hipMemsetAsync(cursor, 0, (size_t)n * sizeof(int), stream);
  for (int k = 0; k < 4; ++k)
    hist_dst<<<(nE[k] + 255) / 256, 256, 0, stream>>>(edges[k] + nE[k], nE[k], cursor);
  scan_blocks<<<nb, 1024, 0, stream>>>(cursor, row_ptr, bsum, n);
  scan_bsums<<<1, 1024, 0, stream>>>(bsum, row_ptr, nb, n);
  scan_add<<<(n + 255) / 256, 256, 0, stream>>>(row_ptr, cursor, bsum, n);
  for (int k = 0; k < 4; ++k)
    scatter_idx<<<(nE[k] + 255) / 256, 256, 0, stream>>>(edges[k], edges[k] + nE[k],
                                                         nE[k], k, cursor, col_idx);

  for (int n0 = 0; n0 < n; n0 += chunk_rows) {
    int n1 = n0 + chunk_rows;
    if (n1 > n) n1 = n;
    int rows = n1 - n0;
    int ggrid = (int)(((long long)rows * 64 + 255) / 256);
    gather_agg<<<ggrid, 256, 0, stream>>>(Xb, row_ptr, col_idx, (uint*)S, n0, n1);
    gemm_final<<<(rows + 63) / 64, 256, 0, stream>>>(S, Wt, out, n0, n1);
  }
}

// Round 5
// 1053.177 us; speedup vs baseline: 10.7614x; 1.0225x over previous
//
#include <hip/hip_runtime.h>

// GCLayer: out[dst] += (X @ W_k)[src] over 4 edge sets.
// Round 5: aggregate-first + per-(node,k) CSR sub-ranges -> branch-free gather.
// S_k[dst] = sum X[src] (bf16), out = concat_k(S_k) @ stack_k(W_k) via MFMA.

#define H 128

typedef __bf16 bf16x8 __attribute__((ext_vector_type(8)));
typedef float f32x4 __attribute__((ext_vector_type(4)));

static __device__ __forceinline__ ushort f2bf(float f) {
  union { float f; uint u; } v; v.f = f;
  uint r = (v.u + 0x7FFFu + ((v.u >> 16) & 1u)) >> 16;
  return (ushort)r;
}
static __device__ __forceinline__ float bflo(uint u) {
  union { uint u; float f; } v; v.u = u << 16; return v.f;
}
static __device__ __forceinline__ float bfhi(uint u) {
  union { uint u; float f; } v; v.u = u & 0xFFFF0000u; return v.f;
}

// ---------------------------------------------------------------------------
// Wt[k][c][kk] = bf16(W_k[kk][c])  (transpose + convert)
// ---------------------------------------------------------------------------
__global__ __launch_bounds__(256) void prep_w(const float* __restrict__ W0,
                                              const float* __restrict__ W1,
                                              const float* __restrict__ W2,
                                              const float* __restrict__ W3,
                                              ushort* __restrict__ Wt) {
  int idx = blockIdx.x * 256 + threadIdx.x;   // 0..65535
  int kk = idx & 127;
  int c = (idx >> 7) & 127;
  int k = idx >> 14;
  const float* W = (k == 0) ? W0 : (k == 1) ? W1 : (k == 2) ? W2 : W3;
  Wt[idx] = f2bf(W[kk * 128 + c]);
}

// ---------------------------------------------------------------------------
// Xb = bf16(X), packed 2 per uint
// ---------------------------------------------------------------------------
__global__ __launch_bounds__(256) void conv_x(const float4* __restrict__ X4,
                                              uint2* __restrict__ Xb2, int m) {
  int i = blockIdx.x * 256 + threadIdx.x;
  if (i < m) {
    float4 v = X4[i];
    uint2 p;
    p.x = (uint)f2bf(v.x) | ((uint)f2bf(v.y) << 16);
    p.y = (uint)f2bf(v.z) | ((uint)f2bf(v.w) << 16);
    Xb2[i] = p;
  }
}

// ---------------------------------------------------------------------------
// CSR over flattened [node][k] segments (4N segments)
// ---------------------------------------------------------------------------
__global__ __launch_bounds__(256) void hist_dst4(const int* __restrict__ dst,
                                                 int nE, int k,
                                                 int* __restrict__ cnt4) {
  int i = blockIdx.x * 256 + threadIdx.x;
  if (i < nE) atomicAdd(&cnt4[dst[i] * 4 + k], 1);
}

// 3-pass decoupled scan ------------------------------------------------------
__global__ __launch_bounds__(1024) void scan_blocks(const int* __restrict__ cnt,
                                                    int* __restrict__ row_ptr,
                                                    int* __restrict__ bsum, int n) {
  __shared__ int wsum[16];
  const int t = threadIdx.x, lane = t & 63, wid = t >> 6;
  int i = blockIdx.x * 1024 + t;
  int v = (i < n) ? cnt[i] : 0;
  int incl = v;
#pragma unroll
  for (int d = 1; d < 64; d <<= 1) {
    int x = __shfl_up(incl, d, 64);
    if (lane >= d) incl += x;
  }
  if (lane == 63) wsum[wid] = incl;
  __syncthreads();
  if (wid == 0 && lane < 16) {
    int w = wsum[lane];
    int wincl = w;
#pragma unroll
    for (int d = 1; d < 16; d <<= 1) {
      int x = __shfl_up(wincl, d, 16);
      if (lane >= d) wincl += x;
    }
    wsum[lane] = wincl - w;   // exclusive wave offset
  }
  __syncthreads();
  int excl = wsum[wid] + (incl - v);
  if (i < n) row_ptr[i] = excl;
  if (t == 1023) bsum[blockIdx.x] = excl + v;   // block total
}

__global__ __launch_bounds__(1024) void scan_bsums(int* __restrict__ bsum,
                                                   int* __restrict__ row_ptr,
                                                   int G, int n) {
  __shared__ int wsum[16];
  const int t = threadIdx.x, lane = t & 63, wid = t >> 6;
  int v = (t < G) ? bsum[t] : 0;
  int incl = v;
#pragma unroll
  for (int d = 1; d < 64; d <<= 1) {
    int x = __shfl_up(incl, d, 64);
    if (lane >= d) incl += x;
  }
  if (lane == 63) wsum[wid] = incl;
  __syncthreads();
  if (wid == 0 && lane < 16) {
    int w = wsum[lane];
    int wincl = w;
#pragma unroll
    for (int d = 1; d < 16; d <<= 1) {
      int x = __shfl_up(wincl, d, 16);
      if (lane >= d) wincl += x;
    }
    wsum[lane] = wincl - w;
  }
  __syncthreads();
  int excl = wsum[wid] + (incl - v);
  if (t < G) bsum[t] = excl;
  if (t == G - 1) row_ptr[n] = excl + v;   // grand total
}

__global__ __launch_bounds__(256) void scan_add(int* __restrict__ row_ptr,
                                                int* __restrict__ cursor,
                                                const int* __restrict__ bsum, int n) {
  int i = blockIdx.x * 256 + threadIdx.x;
  if (i < n) {
    int r = row_ptr[i] + bsum[i >> 10];
    row_ptr[i] = r;
    cursor[i] = r;
  }
}

// scatter plain src ids into col_idx (segment = dst*4+k) --------------------
__global__ __launch_bounds__(256) void scatter_idx4(const int* __restrict__ src,
                                                    const int* __restrict__ dst,
                                                    int nE, int k,
                                                    int* __restrict__ cursor4,
                                                    int* __restrict__ col_idx) {
  int i = blockIdx.x * 256 + threadIdx.x;
  if (i < nE) {
    int pos = atomicAdd(&cursor4[dst[i] * 4 + k], 1);
    col_idx[pos] = src[i];
  }
}

// ---------------------------------------------------------------------------
// Gather-aggregate: one wave per node; branch-free per-k sub-loops.
// Writes S[node-n0][512] bf16 (concat of the 4 k-slices along K).
// ---------------------------------------------------------------------------
__global__ __launch_bounds__(256) void gather_agg(const uint* __restrict__ Xb,
                                                  const int* __restrict__ rp4,
                                                  const int* __restrict__ col_idx,
                                                  uint* __restrict__ S,
                                                  int n0, int n1) {
  int node = n0 + (int)((blockIdx.x * 256 + threadIdx.x) >> 6);
  if (node >= n1) return;
  int lane = threadIdx.x & 63;
  const int* rp = rp4 + (size_t)node * 4;
  size_t rb = (size_t)(node - n0) * 256;   // 512 bf16 = 256 uints per row

#pragma unroll
  for (int k = 0; k < 4; ++k) {
    int beg = rp[k], end = rp[k + 1];
    float ax = 0.f, ay = 0.f, bx = 0.f, by = 0.f;
    int j = beg;
    for (; j + 3 < end; j += 4) {
      int c0 = col_idx[j], c1 = col_idx[j + 1];
      int c2 = col_idx[j + 2], c3 = col_idx[j + 3];
      uint u0 = Xb[(size_t)c0 * 64 + lane];
      uint u1 = Xb[(size_t)c1 * 64 + lane];
      uint u2 = Xb[(size_t)c2 * 64 + lane];
      uint u3 = Xb[(size_t)c3 * 64 + lane];
      ax += bflo(u0); ay += bfhi(u0);
      bx += bflo(u1); by += bfhi(u1);
      ax += bflo(u2); ay += bfhi(u2);
      bx += bflo(u3); by += bfhi(u3);
    }
    for (; j < end; ++j) {
      uint u = Xb[(size_t)col_idx[j] * 64 + lane];
      ax += bflo(u); ay += bfhi(u);
    }
    float rx = ax + bx, ry = ay + by;
    S[rb + (size_t)k * 64 + lane] = (uint)f2bf(rx) | ((uint)f2bf(ry) << 16);
  }
}

// ---------------------------------------------------------------------------
// Final GEMM: out[n0:n1] = S @ concat_k(W_k)   (K=512, bf16 MFMA, fp32 out)
// ---------------------------------------------------------------------------
__global__ __launch_bounds__(256) void gemm_final(const ushort* __restrict__ S,
                                                  const ushort* __restrict__ Wt,
                                                  float* __restrict__ out,
                                                  int n0, int n1) {
  __shared__ __align__(16) ushort sX[64][136];
  __shared__ __align__(16) ushort sW[128][136];

  int row0 = n0 + blockIdx.x * 64;
  int w = threadIdx.x >> 6;
  int l = threadIdx.x & 63;
  int lr = l & 15;
  int lg = l >> 4;

  f32x4 acc[8];
#pragma unroll
  for (int i = 0; i < 8; ++i) acc[i] = (f32x4)0.f;

  for (int kc = 0; kc < 4; ++kc) {
    __syncthreads();
    for (int i = threadIdx.x; i < 1024; i += 256) {
      int r = i >> 4, q = i & 15;
      int gr = row0 + r;
      uint4 v = make_uint4(0u, 0u, 0u, 0u);
      if (gr < n1) v = ((const uint4*)S)[(size_t)(gr - n0) * 64 + kc * 16 + q];
      *(uint4*)&sX[r][q * 8] = v;
    }
    for (int i = threadIdx.x; i < 2048; i += 256) {
      int r = i >> 4, q = i & 15;
      uint4 v = ((const uint4*)Wt)[kc * 2048 + i];
      *(uint4*)&sW[r][q * 8] = v;
    }
    __syncthreads();

#pragma unroll
    for (int kk = 0; kk < 4; ++kk) {
      bf16x8 a = *(const bf16x8*)&sX[w * 16 + lr][kk * 32 + lg * 8];
#pragma unroll
      for (int nf = 0; nf < 8; ++nf) {
        bf16x8 b = *(const bf16x8*)&sW[nf * 16 + lr][kk * 32 + lg * 8];
        acc[nf] = __builtin_amdgcn_mfma_f32_16x16x32_bf16(a, b, acc[nf], 0, 0, 0);
      }
    }
  }

#pragma unroll
  for (int nf = 0; nf < 8; ++nf) {
#pragma unroll
    for (int r = 0; r < 4; ++r) {
      int row = row0 + w * 16 + lg * 4 + r;
      if (row < n1) out[(size_t)row * H + nf * 16 + lr] = acc[nf][r];
    }
  }
}

// ---------------------------------------------------------------------------
extern "C" void kernel_launch(void* const* d_in, const int* in_sizes, int n_in,
                              void* d_out, int out_size, void* d_ws, size_t ws_size,
                              hipStream_t stream) {
  const float* X = (const float*)d_in[0];
  const int* edges[4] = {(const int*)d_in[1], (const int*)d_in[2],
                         (const int*)d_in[3], (const int*)d_in[4]};
  const float* Wk[4] = {(const float*)d_in[5], (const float*)d_in[6],
                        (const float*)d_in[7], (const float*)d_in[8]};
  float* out = (float*)d_out;

  int n = in_sizes[0] / H;
  int nE[4];
  long long totE = 0;
  for (int k = 0; k < 4; ++k) {
    nE[k] = in_sizes[1 + k] / 2;
    totE += nE[k];
  }
  int n4 = n * 4;                       // flattened segments
  int nb4 = (n4 + 1023) / 1024;

  // workspace layout
  char* ws = (char*)d_ws;
  size_t off = 0;
  auto take = [&](size_t bytes) -> char* {
    char* p = ws + off;
    off = (off + bytes + 255) & ~(size_t)255;
    return p;
  };
  ushort* Wt = (ushort*)take(4 * 128 * 128 * sizeof(ushort));
  int* rp4 = (int*)take((size_t)(n4 + 1) * sizeof(int));
  int* cursor4 = (int*)take((size_t)n4 * sizeof(int));
  int* bsum = (int*)take((size_t)nb4 * sizeof(int));
  uint* Xb = (uint*)take((size_t)n * H * sizeof(ushort));
  int* col_idx = (int*)take((size_t)totE * sizeof(int));
  ushort* S = (ushort*)(ws + off);
  size_t s_avail = (ws_size > off) ? (ws_size - off) : 0;

  // node chunking so S (1024 B/node) fits in remaining workspace
  int chunk_rows = (int)(s_avail / 1024);
  if (chunk_rows > n) chunk_rows = n;
  if (chunk_rows < 1024) chunk_rows = 1024;
  chunk_rows &= ~63;

  prep_w<<<256, 256, 0, stream>>>(Wk[0], Wk[1], Wk[2], Wk[3], Wt);
  conv_x<<<(n * 32 + 255) / 256, 256, 0, stream>>>((const float4*)X, (uint2*)Xb, n * 32);

  hipMemsetAsync(cursor4, 0, (size_t)n4 * sizeof(int), stream);
  for (int k = 0; k < 4; ++k)
    hist_dst4<<<(nE[k] + 255) / 256, 256, 0, stream>>>(edges[k] + nE[k], nE[k], k, cursor4);
  scan_blocks<<<nb4, 1024, 0, stream>>>(cursor4, rp4, bsum, n4);
  scan_bsums<<<1, 1024, 0, stream>>>(bsum, rp4, nb4, n4);
  scan_add<<<(n4 + 255) / 256, 256, 0, stream>>>(rp4, cursor4, bsum, n4);
  for (int k = 0; k < 4; ++k)
    scatter_idx4<<<(nE[k] + 255) / 256, 256, 0, stream>>>(edges[k], edges[k] + nE[k],
                                                          nE[k], k, cursor4, col_idx);

  for (int n0 = 0; n0 < n; n0 += chunk_rows) {
    int n1 = n0 + chunk_rows;
    if (n1 > n) n1 = n;
    int rows = n1 - n0;
    int ggrid = (int)(((long long)rows * 64 + 255) / 256);
    gather_agg<<<ggrid, 256, 0, stream>>>(Xb, rp4, col_idx, (uint*)S, n0, n1);
    gemm_final<<<(rows + 63) / 64, 256, 0, stream>>>(S, Wt, out, n0, n1);
  }
}

// Round 6
// 748.263 us; speedup vs baseline: 15.1467x; 1.4075x over previous
//
#include <hip/hip_runtime.h>

// GCLayer: out[dst] += (X @ W_k)[src] over 4 edge sets.
// Round 6: single atomic pass (rank-returning histogram), atomic-free place,
// fused gather+GEMM (S tile lives in LDS only), 9 dispatches total.

#define H 128

typedef __bf16 bf16x8 __attribute__((ext_vector_type(8)));
typedef float f32x4 __attribute__((ext_vector_type(4)));

static __device__ __forceinline__ ushort f2bf(float f) {
  union { float f; uint u; } v; v.f = f;
  uint r = (v.u + 0x7FFFu + ((v.u >> 16) & 1u)) >> 16;
  return (ushort)r;
}
static __device__ __forceinline__ float bflo(uint u) {
  union { uint u; float f; } v; v.u = u << 16; return v.f;
}
static __device__ __forceinline__ float bfhi(uint u) {
  union { uint u; float f; } v; v.u = u & 0xFFFF0000u; return v.f;
}

// ---------------------------------------------------------------------------
// Wt[k][c][kk] = bf16(W_k[kk][c])  (transpose + convert)
// ---------------------------------------------------------------------------
__global__ __launch_bounds__(256) void prep_w(const float* __restrict__ W0,
                                              const float* __restrict__ W1,
                                              const float* __restrict__ W2,
                                              const float* __restrict__ W3,
                                              ushort* __restrict__ Wt) {
  int idx = blockIdx.x * 256 + threadIdx.x;   // 0..65535
  int kk = idx & 127;
  int c = (idx >> 7) & 127;
  int k = idx >> 14;
  const float* W = (k == 0) ? W0 : (k == 1) ? W1 : (k == 2) ? W2 : W3;
  Wt[idx] = f2bf(W[kk * 128 + c]);
}

// ---------------------------------------------------------------------------
// Xb = bf16(X), packed 2 per uint
// ---------------------------------------------------------------------------
__global__ __launch_bounds__(256) void conv_x(const float4* __restrict__ X4,
                                              uint2* __restrict__ Xb2, int m) {
  int i = blockIdx.x * 256 + threadIdx.x;
  if (i < m) {
    float4 v = X4[i];
    uint2 p;
    p.x = (uint)f2bf(v.x) | ((uint)f2bf(v.y) << 16);
    p.y = (uint)f2bf(v.z) | ((uint)f2bf(v.w) << 16);
    Xb2[i] = p;
  }
}

// ---------------------------------------------------------------------------
// Merged histogram over all 4 edge sets; atomicAdd's return value IS the
// within-segment rank -> stored per edge. Grid-stride for ~8 pipelined
// atomics per thread.
// ---------------------------------------------------------------------------
__global__ __launch_bounds__(256) void hist_rank(const int* __restrict__ d0,
                                                 const int* __restrict__ d1,
                                                 const int* __restrict__ d2,
                                                 const int* __restrict__ d3,
                                                 int c1, int c2, int c3, int tot,
                                                 int* __restrict__ cnt4,
                                                 int* __restrict__ rank) {
  int stride = gridDim.x * 256;
  for (int gid = blockIdx.x * 256 + threadIdx.x; gid < tot; gid += stride) {
    int k, i;
    const int* dp;
    if (gid < c1)      { k = 0; i = gid;      dp = d0; }
    else if (gid < c2) { k = 1; i = gid - c1; dp = d1; }
    else if (gid < c3) { k = 2; i = gid - c2; dp = d2; }
    else               { k = 3; i = gid - c3; dp = d3; }
    int seg = dp[i] * 4 + k;
    rank[gid] = atomicAdd(&cnt4[seg], 1);
  }
}

// ---------------------------------------------------------------------------
// Atomic-free placement: col_idx[rp4[seg] + rank[gid]] = src
// ---------------------------------------------------------------------------
__global__ __launch_bounds__(256) void place(const int* __restrict__ s0,
                                             const int* __restrict__ d0,
                                             const int* __restrict__ s1,
                                             const int* __restrict__ d1,
                                             const int* __restrict__ s2,
                                             const int* __restrict__ d2,
                                             const int* __restrict__ s3,
                                             const int* __restrict__ d3,
                                             int c1, int c2, int c3, int tot,
                                             const int* __restrict__ rp4,
                                             const int* __restrict__ rank,
                                             int* __restrict__ col_idx) {
  int gid = blockIdx.x * 256 + threadIdx.x;
  if (gid >= tot) return;
  int k, i;
  const int *dp, *sp;
  if (gid < c1)      { k = 0; i = gid;      dp = d0; sp = s0; }
  else if (gid < c2) { k = 1; i = gid - c1; dp = d1; sp = s1; }
  else if (gid < c3) { k = 2; i = gid - c2; dp = d2; sp = s2; }
  else               { k = 3; i = gid - c3; dp = d3; sp = s3; }
  int seg = dp[i] * 4 + k;
  col_idx[rp4[seg] + rank[gid]] = sp[i];
}

// 3-pass decoupled scan ------------------------------------------------------
__global__ __launch_bounds__(1024) void scan_blocks(const int* __restrict__ cnt,
                                                    int* __restrict__ row_ptr,
                                                    int* __restrict__ bsum, int n) {
  __shared__ int wsum[16];
  const int t = threadIdx.x, lane = t & 63, wid = t >> 6;
  int i = blockIdx.x * 1024 + t;
  int v = (i < n) ? cnt[i] : 0;
  int incl = v;
#pragma unroll
  for (int d = 1; d < 64; d <<= 1) {
    int x = __shfl_up(incl, d, 64);
    if (lane >= d) incl += x;
  }
  if (lane == 63) wsum[wid] = incl;
  __syncthreads();
  if (wid == 0 && lane < 16) {
    int w = wsum[lane];
    int wincl = w;
#pragma unroll
    for (int d = 1; d < 16; d <<= 1) {
      int x = __shfl_up(wincl, d, 16);
      if (lane >= d) wincl += x;
    }
    wsum[lane] = wincl - w;
  }
  __syncthreads();
  int excl = wsum[wid] + (incl - v);
  if (i < n) row_ptr[i] = excl;
  if (t == 1023) bsum[blockIdx.x] = excl + v;
}

__global__ __launch_bounds__(1024) void scan_bsums(int* __restrict__ bsum,
                                                   int* __restrict__ row_ptr,
                                                   int G, int n) {
  __shared__ int wsum[16];
  const int t = threadIdx.x, lane = t & 63, wid = t >> 6;
  int v = (t < G) ? bsum[t] : 0;
  int incl = v;
#pragma unroll
  for (int d = 1; d < 64; d <<= 1) {
    int x = __shfl_up(incl, d, 64);
    if (lane >= d) incl += x;
  }
  if (lane == 63) wsum[wid] = incl;
  __syncthreads();
  if (wid == 0 && lane < 16) {
    int w = wsum[lane];
    int wincl = w;
#pragma unroll
    for (int d = 1; d < 16; d <<= 1) {
      int x = __shfl_up(wincl, d, 16);
      if (lane >= d) wincl += x;
    }
    wsum[lane] = wincl - w;
  }
  __syncthreads();
  int excl = wsum[wid] + (incl - v);
  if (t < G) bsum[t] = excl;
  if (t == G - 1) row_ptr[n] = excl + v;
}

__global__ __launch_bounds__(256) void scan_add(int* __restrict__ row_ptr,
                                                const int* __restrict__ bsum, int n) {
  int i = blockIdx.x * 256 + threadIdx.x;
  if (i < n) row_ptr[i] += bsum[i >> 10];
}

// ---------------------------------------------------------------------------
// Fused gather + GEMM.
// Block: 256 threads = 4 waves; 16 nodes/block.
// Phase 1: wave w gathers nodes (blk*16 + w*4 .. +3): per k-segment, sum
//          Xb rows -> S row (bf16) in LDS.
// Phase 2: out[16x128] = S(16x512) @ Wcat(512x128) via mfma_16x16x32_bf16;
//          A from LDS, B straight from global Wt (131 KB, L2-hot).
// ---------------------------------------------------------------------------
__global__ __launch_bounds__(256, 8) void gg(const uint* __restrict__ Xb,
                                             const int* __restrict__ rp4,
                                             const int* __restrict__ col_idx,
                                             const ushort* __restrict__ Wt,
                                             float* __restrict__ out, int n) {
  __shared__ uint sS[16][260];   // 16 nodes x 256 uints (512 bf16), pad 4

  const int node0 = blockIdx.x * 16;
  const int wave = threadIdx.x >> 6;
  const int lane = threadIdx.x & 63;

  // ---- gather phase ----
#pragma unroll
  for (int i = 0; i < 4; ++i) {
    int local = wave * 4 + i;
    int node = node0 + local;
    if (node < n) {
      const int* rp = rp4 + (size_t)node * 4;
#pragma unroll
      for (int k = 0; k < 4; ++k) {
        int beg = rp[k], end = rp[k + 1];
        float ax = 0.f, ay = 0.f, bx = 0.f, by = 0.f;
        int j = beg;
        for (; j + 3 < end; j += 4) {
          int s0 = col_idx[j], s1 = col_idx[j + 1];
          int s2 = col_idx[j + 2], s3 = col_idx[j + 3];
          uint u0 = Xb[(size_t)s0 * 64 + lane];
          uint u1 = Xb[(size_t)s1 * 64 + lane];
          uint u2 = Xb[(size_t)s2 * 64 + lane];
          uint u3 = Xb[(size_t)s3 * 64 + lane];
          ax += bflo(u0); ay += bfhi(u0);
          bx += bflo(u1); by += bfhi(u1);
          ax += bflo(u2); ay += bfhi(u2);
          bx += bflo(u3); by += bfhi(u3);
        }
        for (; j < end; ++j) {
          uint u = Xb[(size_t)col_idx[j] * 64 + lane];
          ax += bflo(u); ay += bfhi(u);
        }
        float rx = ax + bx, ry = ay + by;
        sS[local][k * 64 + lane] = (uint)f2bf(rx) | ((uint)f2bf(ry) << 16);
      }
    } else {
#pragma unroll
      for (int k = 0; k < 4; ++k) sS[local][k * 64 + lane] = 0u;
    }
  }
  __syncthreads();

  // ---- GEMM phase ----
  const ushort* sSu = (const ushort*)&sS[0][0];   // row stride 520 ushorts
  const int lr = lane & 15;
  const int lg = lane >> 4;
  const int cf0 = wave * 2;                       // this wave's 2 col-frags

  f32x4 acc0 = (f32x4)0.f, acc1 = (f32x4)0.f;

#pragma unroll
  for (int kc = 0; kc < 4; ++kc) {
#pragma unroll
    for (int k4 = 0; k4 < 4; ++k4) {
      bf16x8 a = *(const bf16x8*)&sSu[lr * 520 + kc * 128 + k4 * 32 + lg * 8];
      bf16x8 b0 = *(const bf16x8*)&Wt[kc * 16384 + (cf0 * 16 + lr) * 128 + k4 * 32 + lg * 8];
      bf16x8 b1 = *(const bf16x8*)&Wt[kc * 16384 + ((cf0 + 1) * 16 + lr) * 128 + k4 * 32 + lg * 8];
      acc0 = __builtin_amdgcn_mfma_f32_16x16x32_bf16(a, b0, acc0, 0, 0, 0);
      acc1 = __builtin_amdgcn_mfma_f32_16x16x32_bf16(a, b1, acc1, 0, 0, 0);
    }
  }

#pragma unroll
  for (int r = 0; r < 4; ++r) {
    int row = node0 + lg * 4 + r;
    if (row < n) {
      out[(size_t)row * H + cf0 * 16 + lr] = acc0[r];
      out[(size_t)row * H + (cf0 + 1) * 16 + lr] = acc1[r];
    }
  }
}

// ---------------------------------------------------------------------------
extern "C" void kernel_launch(void* const* d_in, const int* in_sizes, int n_in,
                              void* d_out, int out_size, void* d_ws, size_t ws_size,
                              hipStream_t stream) {
  const float* X = (const float*)d_in[0];
  const int* edges[4] = {(const int*)d_in[1], (const int*)d_in[2],
                         (const int*)d_in[3], (const int*)d_in[4]};
  const float* Wk[4] = {(const float*)d_in[5], (const float*)d_in[6],
                        (const float*)d_in[7], (const float*)d_in[8]};
  float* out = (float*)d_out;

  int n = in_sizes[0] / H;
  int nE[4];
  int tot = 0;
  for (int k = 0; k < 4; ++k) {
    nE[k] = in_sizes[1 + k] / 2;
    tot += nE[k];
  }
  int c1 = nE[0], c2 = c1 + nE[1], c3 = c2 + nE[2];
  int n4 = n * 4;
  int nb4 = (n4 + 1023) / 1024;

  // workspace layout
  char* ws = (char*)d_ws;
  size_t off = 0;
  auto take = [&](size_t bytes) -> char* {
    char* p = ws + off;
    off = (off + bytes + 255) & ~(size_t)255;
    return p;
  };
  ushort* Wt = (ushort*)take(4 * 128 * 128 * sizeof(ushort));
  int* cnt4 = (int*)take((size_t)n4 * sizeof(int));
  int* rp4 = (int*)take((size_t)(n4 + 1) * sizeof(int));
  int* bsum = (int*)take((size_t)nb4 * sizeof(int));
  uint* Xb = (uint*)take((size_t)n * H * sizeof(ushort));
  int* rank = (int*)take((size_t)tot * sizeof(int));
  int* col_idx = (int*)take((size_t)tot * sizeof(int));

  const int* s0 = edges[0];
  const int* d0 = edges[0] + nE[0];
  const int* s1 = edges[1];
  const int* d1 = edges[1] + nE[1];
  const int* s2 = edges[2];
  const int* d2 = edges[2] + nE[2];
  const int* s3 = edges[3];
  const int* d3 = edges[3] + nE[3];

  prep_w<<<256, 256, 0, stream>>>(Wk[0], Wk[1], Wk[2], Wk[3], Wt);
  conv_x<<<(n * 32 + 255) / 256, 256, 0, stream>>>((const float4*)X, (uint2*)Xb, n * 32);

  hipMemsetAsync(cnt4, 0, (size_t)n4 * sizeof(int), stream);
  int hr_grid = (tot + 2047) / 2048;   // ~8 edges/thread
  hist_rank<<<hr_grid, 256, 0, stream>>>(d0, d1, d2, d3, c1, c2, c3, tot,
                                         cnt4, rank);
  scan_blocks<<<nb4, 1024, 0, stream>>>(cnt4, rp4, bsum, n4);
  scan_bsums<<<1, 1024, 0, stream>>>(bsum, rp4, nb4, n4);
  scan_add<<<(n4 + 255) / 256, 256, 0, stream>>>(rp4, bsum, n4);
  place<<<(tot + 255) / 256, 256, 0, stream>>>(s0, d0, s1, d1, s2, d2, s3, d3,
                                               c1, c2, c3, tot, rp4, rank, col_idx);

  gg<<<(n + 15) / 16, 256, 0, stream>>>(Xb, rp4, col_idx, Wt, out, n);
}